// Round 1
// baseline (194.287 us; speedup 1.0000x reference)
//
#include <hip/hip_runtime.h>

typedef __attribute__((ext_vector_type(8))) short short8;
typedef __attribute__((ext_vector_type(4))) float f32x4;

__device__ __forceinline__ unsigned short f2bf(float f) {
  unsigned u = __builtin_bit_cast(unsigned, f);
  u += 0x7fffu + ((u >> 16) & 1u);
  return (unsigned short)(u >> 16);
}

// ---------------- convert f32 -> bf16 (straight copy) ----------------
__global__ __launch_bounds__(256) void cvt_copy(const float* __restrict__ in,
                                                unsigned short* __restrict__ out,
                                                int n4) {
  int i = blockIdx.x * 256 + threadIdx.x;
  if (i >= n4) return;
  float4 v = ((const float4*)in)[i];
  ushort4 o;
  o.x = f2bf(v.x); o.y = f2bf(v.y); o.z = f2bf(v.z); o.w = f2bf(v.w);
  ((ushort4*)out)[i] = o;
}

// ---------------- transpose + convert: in f32 [R][C] -> out bf16 [C][R] ----------------
__global__ __launch_bounds__(256) void transpose_cvt(const float* __restrict__ in,
                                                     unsigned short* __restrict__ out,
                                                     int R, int C) {
  __shared__ float tile[32][33];
  int c0 = blockIdx.x * 32, r0 = blockIdx.y * 32;
  int tx = threadIdx.x, ty = threadIdx.y;
  for (int i = ty; i < 32; i += 8)
    tile[i][tx] = in[(size_t)(r0 + i) * C + c0 + tx];
  __syncthreads();
  for (int i = ty; i < 32; i += 8)
    out[(size_t)(c0 + i) * R + r0 + tx] = f2bf(tile[tx][i]);
}

// ---------------- bf16 GEMM: C[M][N] = A[M][K] * Bt[N][K]^T ----------------
// MODE 0: write Q layout [B,H,Nq,D] bf16 (out0)
// MODE 1: write K layout [B,H,Nkv,D] bf16 (out0) and V^T layout [B,H,D,Nkv] bf16 (out1)
// MODE 2: write f32 out + bias (outf)
template <int MODE>
__global__ __launch_bounds__(256) void gemm_bt(
    const unsigned short* __restrict__ A, const unsigned short* __restrict__ Bt,
    unsigned short* __restrict__ out0, unsigned short* __restrict__ out1,
    float* __restrict__ outf, const float* __restrict__ bias,
    int M, int N, int K) {
  __shared__ __align__(16) unsigned short A_lds[128][72];
  __shared__ __align__(16) unsigned short B_lds[128][72];
  const int tile_m = blockIdx.x * 128;
  const int tile_n = blockIdx.y * 128;
  const int tid = threadIdx.x;
  const int wid = tid >> 6, lane = tid & 63;
  const int wm = (wid >> 1) * 64, wn = (wid & 1) * 64;
  const int lr = lane & 15, lg = lane >> 4;
  f32x4 acc[4][4] = {};

  for (int k0 = 0; k0 < K; k0 += 64) {
    __syncthreads();
#pragma unroll
    for (int p = 0; p < 4; ++p) {
      int flat = p * 256 + tid;
      int row = flat >> 3, cg = (flat & 7) << 3;
      *(short8*)&A_lds[row][cg] = *(const short8*)&A[(size_t)(tile_m + row) * K + k0 + cg];
      *(short8*)&B_lds[row][cg] = *(const short8*)&Bt[(size_t)(tile_n + row) * K + k0 + cg];
    }
    __syncthreads();
    short8 a[4][2], b[4][2];
#pragma unroll
    for (int i = 0; i < 4; ++i)
#pragma unroll
      for (int t = 0; t < 2; ++t) {
        a[i][t] = *(const short8*)&A_lds[wm + i * 16 + lr][t * 32 + lg * 8];
        b[i][t] = *(const short8*)&B_lds[wn + i * 16 + lr][t * 32 + lg * 8];
      }
#pragma unroll
    for (int i = 0; i < 4; ++i)
#pragma unroll
      for (int j = 0; j < 4; ++j)
#pragma unroll
        for (int t = 0; t < 2; ++t)
          acc[i][j] = __builtin_amdgcn_mfma_f32_16x16x32_bf16(a[i][t], b[j][t], acc[i][j], 0, 0, 0);
  }

  // C/D layout (verified m89): col = lane&15, row = (lane>>4)*4 + reg
#pragma unroll
  for (int i = 0; i < 4; ++i)
#pragma unroll
    for (int j = 0; j < 4; ++j)
#pragma unroll
      for (int r = 0; r < 4; ++r) {
        int m = tile_m + wm + i * 16 + lg * 4 + r;
        int n = tile_n + wn + j * 16 + lr;
        float v = acc[i][j][r];
        if (MODE == 0) {
          int b = m >> 11, q = m & 2047;
          int h = n >> 6, d = n & 63;
          out0[((size_t)((b * 12 + h) * 2048 + q) << 6) + d] = f2bf(v);
        } else if (MODE == 1) {
          int b = m >> 11, kv = m & 2047;
          if (n < 768) {
            int h = n >> 6, d = n & 63;
            out0[((size_t)((b * 12 + h) * 2048 + kv) << 6) + d] = f2bf(v);
          } else {
            int h = (n - 768) >> 6, d = n & 63;
            out1[((size_t)((b * 12 + h) * 64 + d) << 11) + kv] = f2bf(v);
          }
        } else {
          outf[(size_t)m * N + n] = v + bias[n];
        }
      }
}

// ---------------- flash attention ----------------
// Q: [B,H,Nq,D] bf16; Kb: [B,H,Nkv,D] bf16; Vt: [B,H,D,Nkv] bf16
// X out: [B,Nq,H*D] bf16.  softmax(QK^T * s) V * s  with s = D^-0.5 = 0.125
__global__ __launch_bounds__(256) void attn_fwd(
    const unsigned short* __restrict__ Q, const unsigned short* __restrict__ Kb,
    const unsigned short* __restrict__ Vt, unsigned short* __restrict__ X) {
  __shared__ __align__(16) unsigned short K_lds[64][72];
  __shared__ __align__(16) unsigned short V_lds[64][72];
  __shared__ __align__(16) unsigned short P_lds[4][16][72];
  const int bh = blockIdx.y;        // b*12 + h
  const int q0 = blockIdx.x * 64;   // 64 q rows per block, 16 per wave
  const int tid = threadIdx.x, wid = tid >> 6, lane = tid & 63;
  const int lr = lane & 15, lg = lane >> 4;
  const float LOG2E = 1.4426950408889634f;

  short8 qf[2];
  {
    const unsigned short* Qp = Q + ((size_t)bh * 2048 + q0 + wid * 16 + lr) * 64;
#pragma unroll
    for (int t = 0; t < 2; ++t) qf[t] = *(const short8*)&Qp[t * 32 + lg * 8];
  }
  f32x4 accO[4] = {};
  float m_r[4], l_r[4];
#pragma unroll
  for (int r = 0; r < 4; ++r) { m_r[r] = -1e30f; l_r[r] = 0.f; }

  const unsigned short* Kbase = Kb + (size_t)bh * (2048 * 64);
  const unsigned short* Vbase = Vt + (size_t)bh * (64 * 2048);

  for (int kv0 = 0; kv0 < 2048; kv0 += 64) {
    __syncthreads();
#pragma unroll
    for (int p = 0; p < 2; ++p) {
      int flat = p * 256 + tid;
      int row = flat >> 3, cg = (flat & 7) << 3;
      *(short8*)&K_lds[row][cg] = *(const short8*)&Kbase[(size_t)(kv0 + row) * 64 + cg];
      *(short8*)&V_lds[row][cg] = *(const short8*)&Vbase[(size_t)row * 2048 + kv0 + cg];
    }
    __syncthreads();

    // S = Q K^T  (16q x 64kv per wave), scaled
    f32x4 s[4] = {};
#pragma unroll
    for (int j = 0; j < 4; ++j)
#pragma unroll
      for (int t = 0; t < 2; ++t) {
        short8 kf = *(const short8*)&K_lds[j * 16 + lr][t * 32 + lg * 8];
        s[j] = __builtin_amdgcn_mfma_f32_16x16x32_bf16(qf[t], kf, s[j], 0, 0, 0);
      }
#pragma unroll
    for (int j = 0; j < 4; ++j) s[j] *= 0.125f;

    // online softmax: rows live at (lane>>4)*4 + r; cols across the 16-lane group
    float rowmax[4];
#pragma unroll
    for (int r = 0; r < 4; ++r)
      rowmax[r] = fmaxf(fmaxf(s[0][r], s[1][r]), fmaxf(s[2][r], s[3][r]));
#pragma unroll
    for (int off = 1; off < 16; off <<= 1)
#pragma unroll
      for (int r = 0; r < 4; ++r)
        rowmax[r] = fmaxf(rowmax[r], __shfl_xor(rowmax[r], off));

    float alpha[4];
#pragma unroll
    for (int r = 0; r < 4; ++r) {
      float mn = fmaxf(m_r[r], rowmax[r]);
      alpha[r] = exp2f((m_r[r] - mn) * LOG2E);
      m_r[r] = mn;
    }

    float rsum[4] = {0.f, 0.f, 0.f, 0.f};
#pragma unroll
    for (int j = 0; j < 4; ++j)
#pragma unroll
      for (int r = 0; r < 4; ++r) {
        float p = exp2f((s[j][r] - m_r[r]) * LOG2E);
        rsum[r] += p;
        P_lds[wid][lg * 4 + r][j * 16 + lr] = f2bf(p);
      }
#pragma unroll
    for (int off = 1; off < 16; off <<= 1)
#pragma unroll
      for (int r = 0; r < 4; ++r)
        rsum[r] += __shfl_xor(rsum[r], off);
#pragma unroll
    for (int r = 0; r < 4; ++r) l_r[r] = l_r[r] * alpha[r] + rsum[r];
#pragma unroll
    for (int jd = 0; jd < 4; ++jd)
#pragma unroll
      for (int r = 0; r < 4; ++r) accO[jd][r] *= alpha[r];

    __syncthreads();  // P writes visible; V_lds still valid

    // O += P V   (P: 16q x 64kv as A-frag; Vt rows are d, cols kv as B-frag)
#pragma unroll
    for (int jd = 0; jd < 4; ++jd)
#pragma unroll
      for (int t = 0; t < 2; ++t) {
        short8 pa = *(const short8*)&P_lds[wid][lr][t * 32 + lg * 8];
        short8 vf = *(const short8*)&V_lds[jd * 16 + lr][t * 32 + lg * 8];
        accO[jd] = __builtin_amdgcn_mfma_f32_16x16x32_bf16(pa, vf, accO[jd], 0, 0, 0);
      }
  }

  const int b = bh / 12, h = bh % 12;
#pragma unroll
  for (int jd = 0; jd < 4; ++jd)
#pragma unroll
    for (int r = 0; r < 4; ++r) {
      int q = q0 + wid * 16 + lg * 4 + r;
      int d = jd * 16 + lr;
      float o = (accO[jd][r] / l_r[r]) * 0.125f;  // faithful quirk: extra scale
      X[((size_t)b * 2048 + q) * 768 + h * 64 + d] = f2bf(o);
    }
}

extern "C" void kernel_launch(void* const* d_in, const int* in_sizes, int n_in,
                              void* d_out, int out_size, void* d_ws, size_t ws_size,
                              hipStream_t stream) {
  const float* q_token  = (const float*)d_in[0];
  const float* kv_token = (const float*)d_in[1];
  const float* Wq    = (const float*)d_in[2];
  const float* Wkv   = (const float*)d_in[3];
  const float* Wproj = (const float*)d_in[4];
  const float* bproj = (const float*)d_in[5];
  float* out = (float*)d_out;

  // workspace carve (all bf16 = ushort elements)
  unsigned short* qb   = (unsigned short*)d_ws;   // [4096][768]
  unsigned short* kvb  = qb   + 3145728;          // [4096][768]
  unsigned short* wqT  = kvb  + 3145728;          // [768][768]
  unsigned short* wkvT = wqT  + 589824;           // [1536][768]
  unsigned short* wpT  = wkvT + 1179648;          // [768][768]
  unsigned short* Qb   = wpT  + 589824;           // [B,H,Nq,D]
  unsigned short* Kbf  = Qb   + 3145728;          // [B,H,Nkv,D]
  unsigned short* Vtb  = Kbf  + 3145728;          // [B,H,D,Nkv]
  unsigned short* Xb   = Vtb  + 3145728;          // [B,Nq,C]

  cvt_copy<<<3072, 256, 0, stream>>>(q_token, qb, 786432);
  cvt_copy<<<3072, 256, 0, stream>>>(kv_token, kvb, 786432);
  transpose_cvt<<<dim3(24, 24), dim3(32, 8), 0, stream>>>(Wq, wqT, 768, 768);
  transpose_cvt<<<dim3(48, 24), dim3(32, 8), 0, stream>>>(Wkv, wkvT, 768, 1536);
  transpose_cvt<<<dim3(24, 24), dim3(32, 8), 0, stream>>>(Wproj, wpT, 768, 768);

  gemm_bt<0><<<dim3(32, 6),  256, 0, stream>>>(qb,  wqT,  Qb,  nullptr, nullptr, nullptr, 4096, 768, 768);
  gemm_bt<1><<<dim3(32, 12), 256, 0, stream>>>(kvb, wkvT, Kbf, Vtb,     nullptr, nullptr, 4096, 1536, 768);

  attn_fwd<<<dim3(32, 24), 256, 0, stream>>>(Qb, Kbf, Vtb, Xb);

  gemm_bt<2><<<dim3(32, 6), 256, 0, stream>>>(Xb, wpT, nullptr, nullptr, out, bproj, 4096, 768, 768);
}